// Round 7
// baseline (936.235 us; speedup 1.0000x reference)
//
#include <hip/hip_runtime.h>

#define NSEQ 256
#define NRES 1024
#define CM   256
#define CC   32
#define CZ   128
#define EPS  1e-5f
#define SROW (NRES * CM)   // stride between s-rows of x for fixed r
#define MCH  16            // m-chunk size (floats)
#define RS   18            // strip row stride (floats): even -> uniform 8-deep writes,
                           // reads max 2-way (free)
#define WSTRIP (64 * RS)   // 1152 floats per wave per buffer

typedef float f4v __attribute__((ext_vector_type(4)));

// ===================== Kernel S: precompute wt[m][c], K1, K2 =====================
__global__ void opm_setup(const float* __restrict__ nw,
                          const float* __restrict__ nb,
                          const float* __restrict__ w_ab,
                          const float* __restrict__ b_ab,
                          float* __restrict__ wt_g,
                          float* __restrict__ k12)
{
    __shared__ float wls[CM * CC];
    const int t = threadIdx.x;          // 256 threads, t == m
    const float nwm = nw[t];
    #pragma unroll
    for (int c = 0; c < CC; ++c)
        wls[t * CC + c] = nwm * w_ab[c * CM + t];
    __syncthreads();
    for (int i = t; i < CM * CC; i += 256) wt_g[i] = wls[i];
    if (t < CC) {
        float k1 = 0.f, k2 = 0.f;
        for (int m = 0; m < CM; ++m) {
            k1 += wls[m * CC + t];
            k2 = fmaf(nb[m], w_ab[t * CM + m], k2);
        }
        k12[t]      = k1;
        k12[CC + t] = k2 + b_ab[t];
    }
}

// ===================== Kernel A: compute pre[r][z] =====================
// One block per residue r. 256 threads = 4 waves, 2 blocks/CU (70 KB LDS).
// G-phase with WAVE-PRIVATE double-buffered strips -> ZERO __syncthreads in
// the 16-chunk loop (no block-wide vmcnt(0)/lgkmcnt(0) drains, no lockstep;
// waves skew freely so loads of one wave overlap FMAs of another).
//   Wave w owns 64 rows: s = 8w + (i&7) + 32*(i>>3), i = 0..63.
//   Staging (per wave): lane l writes f4-slot (l&3) of strip rows i=(l>>2)+16k.
//   Compute (per wave): lane l = 8q+c handles rows i=q+8j (s=8w+q+32j),
//     cols 4c..4c+3; x-read = 8 addrs x 8-lane broadcast (<=2-way, free).
// LDS: wt 32 KB | xa strips 36 KB (reused post-G for P3/P4 scratch) | st 2 KB.
// Epilogue (after the single barrier): P2/P3/P4 verbatim from round 3
// (XOR-swizzled a in the wt region; split-K(4) P3; P4 -> pre workspace).
__launch_bounds__(256, 2)
__global__ void opm_compute(const float* __restrict__ msa,
                            const float* __restrict__ wt_g,
                            const float* __restrict__ k12,
                            const float* __restrict__ w_out,
                            const float* __restrict__ b_out,
                            float* __restrict__ pre_out)
{
    __shared__ float wt[CM * CC];       // 32 KB
    __shared__ float xa[8 * WSTRIP];    // 36 KB: 2 bufs x 4 wave-strips; scratch after G
    __shared__ float st[512];           // per-wave mu/rstd

    const int tid = threadIdx.x;
    const int r   = blockIdx.x;
    const int w   = tid >> 6;           // wave
    const int l   = tid & 63;           // lane

    // staging identity
    const int sl = l & 3;               // f4 slot within 16-float chunk window
    const int si = l >> 2;              // 0..15: strip rows si+16k
    // compute identity
    const int q  = l >> 3;              // row-residue octet 0..7
    const int c  = l & 7;               // col group
    const int c0 = c << 2;

    // strip row i -> global s-row: 8w + (i&7) + 32*(i>>3); for i=si+16k this is
    // brow + 64k with brow = 8w + (si&7) + 32*(si>>3).
    const int brow = (w << 3) + (si & 7) + ((si >> 3) << 5);
    const float* xr = msa + (size_t)r * CM + (sl << 2);

    float* s0 = &xa[w * WSTRIP];
    float* s1 = &xa[(4 + w) * WSTRIP];

    // stage wt[m][c] from global (visible at the single pre-loop barrier)
    #pragma unroll
    for (int k = 0; k < 8; ++k) {
        const int i = (tid + (k << 8)) << 2;
        *(float4*)&wt[i] = *(const float4*)&wt_g[i];
    }

    float G[8][4];
    #pragma unroll
    for (int j = 0; j < 8; ++j) { G[j][0] = 0.f; G[j][1] = 0.f; G[j][2] = 0.f; G[j][3] = 0.f; }
    float psum[4], pssq[4];

    // prologue: chunk 0 -> strip s0 (+stats), chunk 1 -> pf
    float4 pf[4];
    #pragma unroll
    for (int k = 0; k < 4; ++k)
        pf[k] = *(const float4*)(xr + (size_t)(brow + (k << 6)) * SROW);
    #pragma unroll
    for (int k = 0; k < 4; ++k) {
        *(float4*)&s0[(si + (k << 4)) * RS + (sl << 2)] = pf[k];
        psum[k] = (pf[k].x + pf[k].y) + (pf[k].z + pf[k].w);
        pssq[k] = fmaf(pf[k].x, pf[k].x, fmaf(pf[k].y, pf[k].y,
                  fmaf(pf[k].z, pf[k].z, pf[k].w * pf[k].w)));
    }
    #pragma unroll
    for (int k = 0; k < 4; ++k)
        pf[k] = *(const float4*)(xr + (size_t)(brow + (k << 6)) * SROW + MCH);

    __syncthreads();   // wt visible — the ONLY barrier before the epilogue

    float* bR = s0;
    float* bW = s1;
    for (int mb = 0; mb < CM; mb += MCH) {
        const int nxt = mb + MCH;
        if (nxt < CM) {
            // stage next chunk into the alternate private strip (+stats)
            #pragma unroll
            for (int k = 0; k < 4; ++k) {
                *(float4*)&bW[(si + (k << 4)) * RS + (sl << 2)] = pf[k];
                psum[k] += (pf[k].x + pf[k].y) + (pf[k].z + pf[k].w);
                pssq[k]  = fmaf(pf[k].x, pf[k].x, fmaf(pf[k].y, pf[k].y,
                           fmaf(pf[k].z, pf[k].z, fmaf(pf[k].w, pf[k].w, pssq[k]))));
            }
            if (nxt + MCH < CM) {
                #pragma unroll
                for (int k = 0; k < 4; ++k)
                    pf[k] = *(const float4*)(xr + (size_t)(brow + (k << 6)) * SROW + (nxt + MCH));
            }
        }
        // compute chunk mb from this wave's private read strip
        #pragma unroll
        for (int mm = 0; mm < MCH; mm += 4) {
            const float4 w0 = *(const float4*)&wt[(mb + mm + 0) * CC + c0];
            const float4 w1 = *(const float4*)&wt[(mb + mm + 1) * CC + c0];
            const float4 w2 = *(const float4*)&wt[(mb + mm + 2) * CC + c0];
            const float4 w3 = *(const float4*)&wt[(mb + mm + 3) * CC + c0];
            #pragma unroll
            for (int j = 0; j < 8; ++j) {
                const float4 x4 = *(const float4*)&bR[(q + (j << 3)) * RS + mm];
                G[j][0] = fmaf(x4.x, w0.x, fmaf(x4.y, w1.x, fmaf(x4.z, w2.x, fmaf(x4.w, w3.x, G[j][0]))));
                G[j][1] = fmaf(x4.x, w0.y, fmaf(x4.y, w1.y, fmaf(x4.z, w2.y, fmaf(x4.w, w3.y, G[j][1]))));
                G[j][2] = fmaf(x4.x, w0.z, fmaf(x4.y, w1.z, fmaf(x4.z, w2.z, fmaf(x4.w, w3.z, G[j][2]))));
                G[j][3] = fmaf(x4.x, w0.w, fmaf(x4.y, w1.w, fmaf(x4.z, w2.w, fmaf(x4.w, w3.w, G[j][3]))));
            }
        }
        float* t = bR; bR = bW; bW = t;   // wave-local swap, no barrier
    }

    // ---- stats: reduce over the 4 stager-lanes, publish per-wave mu/rstd ----
    #pragma unroll
    for (int k = 0; k < 4; ++k) {
        float a1 = psum[k], a2 = pssq[k];
        a1 += __shfl_xor(a1, 1); a1 += __shfl_xor(a1, 2);
        a2 += __shfl_xor(a2, 1); a2 += __shfl_xor(a2, 2);
        if (sl == 0) {
            const int i = si + (k << 4);
            const float mu  = a1 * (1.f / CM);
            const float var = a2 * (1.f / CM) - mu * mu;
            st[(w << 7) + i]      = mu;
            st[(w << 7) + 64 + i] = 1.f / sqrtf(var + EPS);
        }
    }
    __syncthreads();   // (A) all wt/strip reads done; stats visible

    // ---------------- P2: finalize a -> wt region, XOR-swizzled f4 slots ----------------
    {
        const float4 k1v = *(const float4*)&k12[c0];
        const float4 k2v = *(const float4*)&k12[CC + c0];
        #pragma unroll
        for (int j = 0; j < 8; ++j) {
            const int i = q + (j << 3);                 // strip index
            const int s = (w << 3) + q + (j << 5);      // global s-row; s&7 == q
            const float mu   = st[(w << 7) + i];
            const float rstd = st[(w << 7) + 64 + i];
            float4 av;
            av.x = fmaf(rstd, G[j][0] - mu * k1v.x, k2v.x);
            av.y = fmaf(rstd, G[j][1] - mu * k1v.y, k2v.y);
            av.z = fmaf(rstd, G[j][2] - mu * k1v.z, k2v.z);
            av.w = fmaf(rstd, G[j][3] - mu * k1v.w, k2v.w);
            *(float4*)&wt[s * CC + ((c ^ q) << 2)] = av;
        }
    }
    __syncthreads();   // (C) a complete (partials may overwrite xa)

    // ---------------- P3: o = A^T A / NSEQ, split-K(4) x 4x4 tiles ----------------
    const int grp = w;                 // s-slice 64*grp .. +63
    const int xs_ = (tid >> 3) & 7;    // row f4-slot
    const int ys_ = tid & 7;           // col f4-slot
    float4 pr0 = {0,0,0,0}, pr1 = {0,0,0,0}, pr2 = {0,0,0,0}, pr3 = {0,0,0,0};
    #pragma unroll 4
    for (int si_ = 0; si_ < 64; ++si_) {
        const int s  = (grp << 6) + si_;
        const int sw = s & 7;
        const float4 ax = *(const float4*)&wt[s * CC + ((xs_ ^ sw) << 2)];
        const float4 ay = *(const float4*)&wt[s * CC + ((ys_ ^ sw) << 2)];
        pr0.x = fmaf(ax.x, ay.x, pr0.x); pr0.y = fmaf(ax.x, ay.y, pr0.y);
        pr0.z = fmaf(ax.x, ay.z, pr0.z); pr0.w = fmaf(ax.x, ay.w, pr0.w);
        pr1.x = fmaf(ax.y, ay.x, pr1.x); pr1.y = fmaf(ax.y, ay.y, pr1.y);
        pr1.z = fmaf(ax.y, ay.z, pr1.z); pr1.w = fmaf(ax.y, ay.w, pr1.w);
        pr2.x = fmaf(ax.z, ay.x, pr2.x); pr2.y = fmaf(ax.z, ay.y, pr2.y);
        pr2.z = fmaf(ax.z, ay.z, pr2.z); pr2.w = fmaf(ax.z, ay.w, pr2.w);
        pr3.x = fmaf(ax.w, ay.x, pr3.x); pr3.y = fmaf(ax.w, ay.y, pr3.y);
        pr3.z = fmaf(ax.w, ay.z, pr3.z); pr3.w = fmaf(ax.w, ay.w, pr3.w);
    }
    {   // partials into xa (strips dead)
        float* pb = &xa[(grp << 10) + ((xs_ << 2) * CC) + (ys_ << 2)];
        *(float4*)&pb[0 * CC] = pr0;
        *(float4*)&pb[1 * CC] = pr1;
        *(float4*)&pb[2 * CC] = pr2;
        *(float4*)&pb[3 * CC] = pr3;
    }
    __syncthreads();   // (D) partials visible
    {   // reduce 4 partials -> o at xa[0..1023]
        const float inv_s = 1.f / NSEQ;
        float4 acc = *(const float4*)&xa[(tid << 2)];
        const float4 b1 = *(const float4*)&xa[1024 + (tid << 2)];
        const float4 b2 = *(const float4*)&xa[2048 + (tid << 2)];
        const float4 b3 = *(const float4*)&xa[3072 + (tid << 2)];
        acc.x = (acc.x + b1.x + b2.x + b3.x) * inv_s;
        acc.y = (acc.y + b1.y + b2.y + b3.y) * inv_s;
        acc.z = (acc.z + b1.z + b2.z + b3.z) * inv_s;
        acc.w = (acc.w + b1.w + b2.w + b3.w) * inv_s;
        *(float4*)&xa[tid << 2] = acc;
    }
    __syncthreads();   // (E) o visible

    // ---------------- P4: pre[z] = o . w_out[z] + b_out[z] ----------------
    {
        const int z    = tid & 127;
        const int half = tid >> 7;
        const float* wrow = w_out + (size_t)z * (CC * CC) + half * 512;
        const float* op   = &xa[half * 512];
        float po = 0.f;
        #pragma unroll 8
        for (int k = 0; k < 512; k += 4) {
            const float4 o4 = *(const float4*)&op[k];
            const float4 w4 = *(const float4*)&wrow[k];
            po = fmaf(o4.x, w4.x, fmaf(o4.y, w4.y, fmaf(o4.z, w4.z, fmaf(o4.w, w4.w, po))));
        }
        xa[4096 + (half << 7) + z] = po;
    }
    __syncthreads();   // (F)
    if (tid < CZ)
        pre_out[(size_t)r * CZ + tid] = xa[4096 + tid] + xa[4096 + CZ + tid] + b_out[tid];
}

// ===================== Kernel B: broadcast pre over 1024 rows =====================
__launch_bounds__(256, 8)
__global__ void opm_bcast(const float* __restrict__ pre,
                          float* __restrict__ out)
{
    const int bid = blockIdx.x;
    const int r   = bid >> 3;                 // 0..1023
    const int jb  = bid & 7;                  // 128-row slab within the r-plane
    const int z4  = threadIdx.x & 31;         // which float4 of the 128-float row
    const int jo  = threadIdx.x >> 5;         // 0..7

    const f4v pv = *((const f4v*)(pre + (size_t)r * CZ) + z4);
    f4v* outp = (f4v*)out + ((size_t)r * NRES + (size_t)jb * 128) * (CZ / 4);
    for (int j0 = 0; j0 < 128; j0 += 8)
        __builtin_nontemporal_store(pv, &outp[(size_t)(j0 + jo) * (CZ / 4) + z4]);
}

extern "C" void kernel_launch(void* const* d_in, const int* in_sizes, int n_in,
                              void* d_out, int out_size, void* d_ws, size_t ws_size,
                              hipStream_t stream) {
    const float* msa   = (const float*)d_in[0];
    const float* nw    = (const float*)d_in[1];
    const float* nb    = (const float*)d_in[2];
    const float* w_ab  = (const float*)d_in[3];
    const float* b_ab  = (const float*)d_in[4];
    const float* w_out = (const float*)d_in[5];
    const float* b_out = (const float*)d_in[6];
    float* out = (float*)d_out;

    float* pre  = (float*)d_ws;                    // 512 KB
    float* wt_g = pre + (size_t)NRES * CZ;         // 32 KB
    float* k12  = wt_g + CM * CC;                  // 256 B

    opm_setup<<<1, 256, 0, stream>>>(nw, nb, w_ab, b_ab, wt_g, k12);
    opm_compute<<<NRES, 256, 0, stream>>>(msa, wt_g, k12, w_out, b_out, pre);
    opm_bcast<<<NRES * 8, 256, 0, stream>>>(pre, out);
}

// Round 8
// 791.434 us; speedup vs baseline: 1.1830x; 1.1830x over previous
//
#include <hip/hip_runtime.h>

#define NSEQ 256
#define NRES 1024
#define CM   256
#define CC   32
#define CZ   128
#define EPS  1e-5f
#define SROW (NRES * CM)   // stride between s-rows of x for fixed r

typedef float f4v __attribute__((ext_vector_type(4)));
typedef __attribute__((ext_vector_type(8))) short short8;   // bf16x8 MFMA frag
typedef __attribute__((ext_vector_type(4))) float f32x4;    // MFMA acc
typedef unsigned int u32;

__device__ __forceinline__ float trunc_bf16(float f) {
    return __uint_as_float(__float_as_uint(f) & 0xffff0000u);
}
__device__ __forceinline__ u32 pk_bf16(float a, float b) {   // low=a, high=b
    return (__float_as_uint(b) & 0xffff0000u) | (__float_as_uint(a) >> 16);
}

// ===================== Kernel S: K1/K2 + B-fragment-arranged bf16x2 weights =====================
// wt[m][c] = nw[m]*w_ab[c][m];  K1[c]=sum wt;  K2[c]=sum nb*w_ab + b_ab.
// wb_su[e]: e = (((kk*2+nt)*2+split)*64 + lane)*8 + j, holding bf16 split of
// wt[m][c] with m = 32kk + 8*(lane>>4) + j, c = 16nt + (lane&15)  — exactly
// the v_mfma_f32_16x16x32_bf16 B-fragment lane order (col=lane&15,
// k=8*(lane>>4)+j), so the main kernel reads it linearly (conflict-free).
__global__ void opm_setup(const float* __restrict__ nw,
                          const float* __restrict__ nb,
                          const float* __restrict__ w_ab,
                          const float* __restrict__ b_ab,
                          float* __restrict__ k12,
                          unsigned short* __restrict__ wb_su)
{
    __shared__ float wls[CM * CC];
    const int t = threadIdx.x;          // 256 threads, t == m
    const float nwm = nw[t];
    #pragma unroll
    for (int c = 0; c < CC; ++c)
        wls[t * CC + c] = nwm * w_ab[c * CM + t];
    __syncthreads();
    if (t < CC) {
        float k1 = 0.f, k2 = 0.f;
        for (int m = 0; m < CM; ++m) {
            k1 += wls[m * CC + t];
            k2 = fmaf(nb[m], w_ab[t * CM + m], k2);
        }
        k12[t]      = k1;
        k12[CC + t] = k2 + b_ab[t];
    }
    for (int e = t; e < 16384; e += 256) {
        const int j     = e & 7;
        const int l     = (e >> 3) & 63;
        const int split = (e >> 9) & 1;
        const int nt    = (e >> 10) & 1;
        const int kk    = e >> 11;
        const int m = (kk << 5) + ((l >> 4) << 3) + j;
        const int c = (nt << 4) + (l & 15);
        const float w  = wls[m * CC + c];
        const float w1 = trunc_bf16(w);
        const float v  = split ? (w - w1) : w;   // split1 residual re-truncated below
        wb_su[e] = (unsigned short)(__float_as_uint(v) >> 16);
    }
}

// ===================== Kernel A: compute pre[r][z] via MFMA bf16x2 =====================
// One block per residue r. 256 threads = 4 waves, 2 blocks/CU (74 KB LDS).
// G-phase: C[s=256][c=32] = X·Wt as 3 bf16 MFMA products (x1w1+x1w2+x2w1)
// accumulated in fp32; LN folded afterward (a = rstd*(G - mu*K1) + K2) with
// exact fp32 register stats from the staging loads.
//  - staging: t=(sg8=t>>3 rows sg8+32k, sc8=t&7): 128B/8-lane coalesced reads;
//    converts to 2 bf16 planes xp1/xp2 (row stride 20 u32; b128 A-reads land
//    exactly 8/bank = conflict-free), stats from regs.
//  - wave w owns s-rows [64w,64w+64): 4 M-tiles x 2 N-tiles; per 32-m chunk:
//    8 A b128 + 4 B b128 + 24 MFMA (16x16x32).
//  - epilogue P2/P3/P4 verbatim from the round-1/3 verified code.
__launch_bounds__(256, 2)
__global__ void opm_compute(const float* __restrict__ msa,
                            const u32*  __restrict__ wb_g,
                            const float* __restrict__ k12,
                            const float* __restrict__ w_out,
                            const float* __restrict__ b_out,
                            float* __restrict__ pre_out)
{
    __shared__ u32 xp[2 * 5120];       // 40 KB: planes x1,x2 (256 rows x 20 u32); a[s][32] after
    __shared__ u32 wbl[8192];          // 32 KB: B-frags; P3/P4 scratch after
    __shared__ float st[520];          // mu [0..255], rstd [256..511]

    const int tid = threadIdx.x;
    const int r   = blockIdx.x;
    const int w   = tid >> 6;           // wave 0..3
    const int l   = tid & 63;

    // staging identity
    const int sc8 = tid & 7;            // f4 slot within 32-float chunk row
    const int sg8 = tid >> 3;           // 0..31; rows sg8+32k
    const float* xr = msa + (size_t)r * CM + (sc8 << 2);

    u32* xp1 = xp;
    u32* xp2 = xp + 5120;

    // stage B-fragments (8192 u32) from global
    #pragma unroll
    for (int k = 0; k < 8; ++k) {
        const int i = (tid + (k << 8)) << 2;
        *(f4v*)&wbl[i] = *(const f4v*)&wb_g[i];
    }

    f32x4 acc[4][2];
    #pragma unroll
    for (int mt = 0; mt < 4; ++mt) { acc[mt][0] = (f32x4)0.f; acc[mt][1] = (f32x4)0.f; }
    float psum[8], pssq[8];
    #pragma unroll
    for (int k = 0; k < 8; ++k) { psum[k] = 0.f; pssq[k] = 0.f; }

    // prologue: prefetch chunk 0 (8 lanes cover 128B contiguous per row)
    float4 pf[8];
    #pragma unroll
    for (int k = 0; k < 8; ++k)
        pf[k] = *(const float4*)(xr + (size_t)(sg8 + (k << 5)) * SROW);

    for (int kk = 0; kk < 8; ++kk) {
        __syncthreads();   // previous chunk's readers done
        #pragma unroll
        for (int k = 0; k < 8; ++k) {
            const float4 p = pf[k];
            const int row = sg8 + (k << 5);
            const u32 a0 = pk_bf16(p.x, p.y), a1 = pk_bf16(p.z, p.w);
            const float rx = p.x - trunc_bf16(p.x);
            const float ry = p.y - trunc_bf16(p.y);
            const float rz = p.z - trunc_bf16(p.z);
            const float rw = p.w - trunc_bf16(p.w);
            const u32 b0 = pk_bf16(rx, ry), b1 = pk_bf16(rz, rw);
            *(uint2*)&xp1[row * 20 + (sc8 << 1)] = make_uint2(a0, a1);
            *(uint2*)&xp2[row * 20 + (sc8 << 1)] = make_uint2(b0, b1);
            psum[k] += (p.x + p.y) + (p.z + p.w);
            pssq[k]  = fmaf(p.x, p.x, fmaf(p.y, p.y, fmaf(p.z, p.z, fmaf(p.w, p.w, pssq[k]))));
        }
        __syncthreads();   // chunk planes (and, first time, wbl) visible
        if (kk < 7) {
            #pragma unroll
            for (int k = 0; k < 8; ++k)
                pf[k] = *(const float4*)(xr + (size_t)(sg8 + (k << 5)) * SROW + ((kk + 1) << 5));
        }
        // B-frags for this k-step: (nt, split)
        short8 B[2][2];
        #pragma unroll
        for (int nt = 0; nt < 2; ++nt)
            #pragma unroll
            for (int sp = 0; sp < 2; ++sp) {
                const int fb = ((((kk << 1) + nt) << 1) + sp) * 256 + (l << 2);
                B[nt][sp] = __builtin_bit_cast(short8, *(const f4v*)&wbl[fb]);
            }
        // A-frags + MFMA
        #pragma unroll
        for (int mt = 0; mt < 4; ++mt) {
            const int arow = ((w << 6) + (mt << 4) + (l & 15)) * 20 + ((l >> 4) << 2);
            const short8 A1 = __builtin_bit_cast(short8, *(const f4v*)&xp1[arow]);
            const short8 A2 = __builtin_bit_cast(short8, *(const f4v*)&xp2[arow]);
            acc[mt][0] = __builtin_amdgcn_mfma_f32_16x16x32_bf16(A1, B[0][0], acc[mt][0], 0, 0, 0);
            acc[mt][1] = __builtin_amdgcn_mfma_f32_16x16x32_bf16(A1, B[1][0], acc[mt][1], 0, 0, 0);
            acc[mt][0] = __builtin_amdgcn_mfma_f32_16x16x32_bf16(A1, B[0][1], acc[mt][0], 0, 0, 0);
            acc[mt][1] = __builtin_amdgcn_mfma_f32_16x16x32_bf16(A1, B[1][1], acc[mt][1], 0, 0, 0);
            acc[mt][0] = __builtin_amdgcn_mfma_f32_16x16x32_bf16(A2, B[0][0], acc[mt][0], 0, 0, 0);
            acc[mt][1] = __builtin_amdgcn_mfma_f32_16x16x32_bf16(A2, B[1][0], acc[mt][1], 0, 0, 0);
        }
    }
    __syncthreads();   // (A) all plane reads done

    // ---- stats: reduce over the 8 sc8-lanes, publish mu/rstd ----
    #pragma unroll
    for (int k = 0; k < 8; ++k) {
        float s1 = psum[k], s2 = pssq[k];
        s1 += __shfl_xor(s1, 1); s1 += __shfl_xor(s1, 2); s1 += __shfl_xor(s1, 4);
        s2 += __shfl_xor(s2, 1); s2 += __shfl_xor(s2, 2); s2 += __shfl_xor(s2, 4);
        if (sc8 == 0) {
            const int s = sg8 + (k << 5);
            const float mu  = s1 * (1.f / CM);
            const float var = s2 * (1.f / CM) - mu * mu;
            st[s]        = mu;
            st[256 + s]  = 1.f / sqrtf(var + EPS);
        }
    }
    __syncthreads();   // (B) mu/rstd visible

    // ---------------- P2: LN-fold -> a[s][32] in plane region, XOR-swizzled ----------------
    float* aB = (float*)xp;
    {
        const int cl = l & 15;
        const float k1_0 = k12[cl],      k1_1 = k12[16 + cl];
        const float k2_0 = k12[CC + cl], k2_1 = k12[CC + 16 + cl];
        #pragma unroll
        for (int mt = 0; mt < 4; ++mt) {
            #pragma unroll
            for (int rg = 0; rg < 4; ++rg) {
                const int s = (w << 6) + (mt << 4) + ((l >> 4) << 2) + rg;
                const float mu = st[s], rs = st[256 + s];
                const float a0 = fmaf(rs, acc[mt][0][rg] - mu * k1_0, k2_0);
                const float a1 = fmaf(rs, acc[mt][1][rg] - mu * k1_1, k2_1);
                const int sw = s & 7;
                aB[s * CC + (((cl >> 2) ^ sw) << 2) + (cl & 3)]       = a0;
                aB[s * CC + ((((cl >> 2) + 4) ^ sw) << 2) + (cl & 3)] = a1;
            }
        }
    }
    __syncthreads();   // (C) a complete (scratch may overwrite wbl)

    // ---------------- P3: o = A^T A / NSEQ, split-K(4) x 4x4 tiles ----------------
    float* scr = (float*)wbl;
    const int grp = w;                 // s-slice 64*grp .. +63
    const int xs_ = (tid >> 3) & 7;    // row f4-slot
    const int ys_ = tid & 7;           // col f4-slot
    float4 pr0 = {0,0,0,0}, pr1 = {0,0,0,0}, pr2 = {0,0,0,0}, pr3 = {0,0,0,0};
    #pragma unroll 4
    for (int si = 0; si < 64; ++si) {
        const int s  = (grp << 6) + si;
        const int sw = s & 7;
        const float4 ax = *(const float4*)&aB[s * CC + ((xs_ ^ sw) << 2)];
        const float4 ay = *(const float4*)&aB[s * CC + ((ys_ ^ sw) << 2)];
        pr0.x = fmaf(ax.x, ay.x, pr0.x); pr0.y = fmaf(ax.x, ay.y, pr0.y);
        pr0.z = fmaf(ax.x, ay.z, pr0.z); pr0.w = fmaf(ax.x, ay.w, pr0.w);
        pr1.x = fmaf(ax.y, ay.x, pr1.x); pr1.y = fmaf(ax.y, ay.y, pr1.y);
        pr1.z = fmaf(ax.y, ay.z, pr1.z); pr1.w = fmaf(ax.y, ay.w, pr1.w);
        pr2.x = fmaf(ax.z, ay.x, pr2.x); pr2.y = fmaf(ax.z, ay.y, pr2.y);
        pr2.z = fmaf(ax.z, ay.z, pr2.z); pr2.w = fmaf(ax.z, ay.w, pr2.w);
        pr3.x = fmaf(ax.w, ay.x, pr3.x); pr3.y = fmaf(ax.w, ay.y, pr3.y);
        pr3.z = fmaf(ax.w, ay.z, pr3.z); pr3.w = fmaf(ax.w, ay.w, pr3.w);
    }
    {
        float* pb = &scr[(grp << 10) + ((xs_ << 2) * CC) + (ys_ << 2)];
        *(float4*)&pb[0 * CC] = pr0;
        *(float4*)&pb[1 * CC] = pr1;
        *(float4*)&pb[2 * CC] = pr2;
        *(float4*)&pb[3 * CC] = pr3;
    }
    __syncthreads();   // (D) partials visible
    {
        const float inv_s = 1.f / NSEQ;
        float4 a4 = *(const float4*)&scr[(tid << 2)];
        const float4 b1 = *(const float4*)&scr[1024 + (tid << 2)];
        const float4 b2 = *(const float4*)&scr[2048 + (tid << 2)];
        const float4 b3 = *(const float4*)&scr[3072 + (tid << 2)];
        a4.x = (a4.x + b1.x + b2.x + b3.x) * inv_s;
        a4.y = (a4.y + b1.y + b2.y + b3.y) * inv_s;
        a4.z = (a4.z + b1.z + b2.z + b3.z) * inv_s;
        a4.w = (a4.w + b1.w + b2.w + b3.w) * inv_s;
        *(float4*)&scr[tid << 2] = a4;
    }
    __syncthreads();   // (E) o visible

    // ---------------- P4: pre[z] = o . w_out[z] + b_out[z] ----------------
    {
        const int z    = tid & 127;
        const int half = tid >> 7;
        const float* wrow = w_out + (size_t)z * (CC * CC) + half * 512;
        const float* op   = &scr[half * 512];
        float po = 0.f;
        #pragma unroll 8
        for (int k = 0; k < 512; k += 4) {
            const float4 o4 = *(const float4*)&op[k];
            const float4 w4 = *(const float4*)&wrow[k];
            po = fmaf(o4.x, w4.x, fmaf(o4.y, w4.y, fmaf(o4.z, w4.z, fmaf(o4.w, w4.w, po))));
        }
        scr[4096 + (half << 7) + z] = po;
    }
    __syncthreads();   // (F)
    if (tid < CZ)
        pre_out[(size_t)r * CZ + tid] = scr[4096 + tid] + scr[4096 + CZ + tid] + b_out[tid];
}

// ===================== Kernel B: broadcast pre over 1024 rows =====================
__launch_bounds__(256, 8)
__global__ void opm_bcast(const float* __restrict__ pre,
                          float* __restrict__ out)
{
    const int bid = blockIdx.x;
    const int r   = bid >> 3;                 // 0..1023
    const int jb  = bid & 7;                  // 128-row slab within the r-plane
    const int z4  = threadIdx.x & 31;         // which float4 of the 128-float row
    const int jo  = threadIdx.x >> 5;         // 0..7

    const f4v pv = *((const f4v*)(pre + (size_t)r * CZ) + z4);
    f4v* outp = (f4v*)out + ((size_t)r * NRES + (size_t)jb * 128) * (CZ / 4);
    for (int j0 = 0; j0 < 128; j0 += 8)
        __builtin_nontemporal_store(pv, &outp[(size_t)(j0 + jo) * (CZ / 4) + z4]);
}

extern "C" void kernel_launch(void* const* d_in, const int* in_sizes, int n_in,
                              void* d_out, int out_size, void* d_ws, size_t ws_size,
                              hipStream_t stream) {
    const float* msa   = (const float*)d_in[0];
    const float* nw    = (const float*)d_in[1];
    const float* nb    = (const float*)d_in[2];
    const float* w_ab  = (const float*)d_in[3];
    const float* b_ab  = (const float*)d_in[4];
    const float* w_out = (const float*)d_in[5];
    const float* b_out = (const float*)d_in[6];
    float* out = (float*)d_out;

    float* pre = (float*)d_ws;                           // [0, 131072) floats
    float* k12 = pre + (size_t)NRES * CZ;                // [131072, 131136)
    unsigned short* wb_su = (unsigned short*)(k12 + 64); // 16384 bf16 (32 KB), 16B-aligned

    opm_setup<<<1, 256, 0, stream>>>(nw, nb, w_ab, b_ab, k12, wb_su);
    opm_compute<<<NRES, 256, 0, stream>>>(msa, (const u32*)wb_su, k12, w_out, b_out, pre);
    opm_bcast<<<NRES * 8, 256, 0, stream>>>(pre, out);
}

// Round 9
// 788.994 us; speedup vs baseline: 1.1866x; 1.0031x over previous
//
#include <hip/hip_runtime.h>

#define NSEQ 256
#define NRES 1024
#define CM   256
#define CC   32
#define CZ   128
#define EPS  1e-5f
#define SROW (NRES * CM)   // stride between s-rows of x for fixed r

typedef float f4v __attribute__((ext_vector_type(4)));
typedef __attribute__((ext_vector_type(8))) short short8;   // bf16x8 MFMA frag
typedef __attribute__((ext_vector_type(4))) float f32x4;    // MFMA acc
typedef unsigned int u32;

__device__ __forceinline__ float trunc_bf16(float f) {
    return __uint_as_float(__float_as_uint(f) & 0xffff0000u);
}
__device__ __forceinline__ u32 pk_bf16(float a, float b) {   // low=a, high=b
    return (__float_as_uint(b) & 0xffff0000u) | (__float_as_uint(a) >> 16);
}

// ===================== Kernel S: K1/K2 + B-fragment-arranged bf16x2 weights =====================
// (verbatim from round 8 — validated end-to-end)
__global__ void opm_setup(const float* __restrict__ nw,
                          const float* __restrict__ nb,
                          const float* __restrict__ w_ab,
                          const float* __restrict__ b_ab,
                          float* __restrict__ k12,
                          unsigned short* __restrict__ wb_su)
{
    __shared__ float wls[CM * CC];
    const int t = threadIdx.x;          // 256 threads, t == m
    const float nwm = nw[t];
    #pragma unroll
    for (int c = 0; c < CC; ++c)
        wls[t * CC + c] = nwm * w_ab[c * CM + t];
    __syncthreads();
    if (t < CC) {
        float k1 = 0.f, k2 = 0.f;
        for (int m = 0; m < CM; ++m) {
            k1 += wls[m * CC + t];
            k2 = fmaf(nb[m], w_ab[t * CM + m], k2);
        }
        k12[t]      = k1;
        k12[CC + t] = k2 + b_ab[t];
    }
    for (int e = t; e < 16384; e += 256) {
        const int j     = e & 7;
        const int l     = (e >> 3) & 63;
        const int split = (e >> 9) & 1;
        const int nt    = (e >> 10) & 1;
        const int kk    = e >> 11;
        const int m = (kk << 5) + ((l >> 4) << 3) + j;
        const int c = (nt << 4) + (l & 15);
        const float w  = wls[m * CC + c];
        const float w1 = trunc_bf16(w);
        const float v  = split ? (w - w1) : w;
        wb_su[e] = (unsigned short)(__float_as_uint(v) >> 16);
    }
}

// ===================== Kernel A: MFMA with DIRECT global->register A-fragments =====================
// One block per residue r. 256 threads = 4 waves, 3 blocks/CU (51 KB LDS).
// The 16x16x32 A-fragment is lane-private: lane l of wave w, tile mt owns row
// (w*64+mt*16+(l&15)), k-slice (l>>4)*8..+8 — 8 CONTIGUOUS floats of msa.
// So x is loaded straight into registers (2 dwordx4/lane/tile), converted to
// bf16x2 planes in-reg, and MFMA'd. NO LDS staging for x: no ds_writes, no A
// ds_reads, no per-chunk barrier pair (2 barriers before epilogue, not 17).
// Per kk iteration: issue 8 next-kk loads -> 4 B ds_read_b128 -> 4x(convert +
// stats + 6 MFMA). Loads stay in flight across the MFMA phase (T14).
// Coalescing: a wave's 64 lanes cover 16 rows x full 128-B line (paired loads
// split each line 4x16B + 4x16B interleaved; L1 serves the second).
// Stats: psum/pssq per (mt) over lane's 8 floats/kk; reduce over k-groups via
// shfl_xor(16/32); lanes l<16 publish. LN fold + P2/P3/P4 epilogue verbatim
// from round 8 (validated); a[s][32] overwrites the dead B-frag region.
__launch_bounds__(256, 3)
__global__ void opm_compute(const float* __restrict__ msa,
                            const u32*  __restrict__ wb_g,
                            const float* __restrict__ k12,
                            const float* __restrict__ w_out,
                            const float* __restrict__ b_out,
                            float* __restrict__ pre_out)
{
    __shared__ u32 wbl[8192];          // 32 KB: B-frags during G; a[s][32] after P2
    __shared__ float scr[4352];        // 17 KB: P3 partials/o + pre_part
    __shared__ float st[512];          // mu [0..255], rstd [256..511]

    const int tid = threadIdx.x;
    const int r   = blockIdx.x;
    const int w   = tid >> 6;           // wave 0..3
    const int l   = tid & 63;
    const int lr  = l & 15;             // row-in-tile / C-col
    const int lk  = l >> 4;             // k-group 0..3

    const float* xr = msa + (size_t)r * CM;
    size_t rowoff[4];
    #pragma unroll
    for (int mt = 0; mt < 4; ++mt)
        rowoff[mt] = (size_t)((w << 6) + (mt << 4) + lr) * SROW + (lk << 3);

    // stage B-fragments (8192 u32) from global
    #pragma unroll
    for (int k = 0; k < 8; ++k) {
        const int i = (tid + (k << 8)) << 2;
        *(f4v*)&wbl[i] = *(const f4v*)&wb_g[i];
    }

    f32x4 acc[4][2];
    #pragma unroll
    for (int mt = 0; mt < 4; ++mt) { acc[mt][0] = (f32x4)0.f; acc[mt][1] = (f32x4)0.f; }
    float psum[4], pssq[4];
    #pragma unroll
    for (int mt = 0; mt < 4; ++mt) { psum[mt] = 0.f; pssq[mt] = 0.f; }

    // prologue: load kk=0 A-data
    float4 curA[4], curB[4], nxtA[4], nxtB[4];
    #pragma unroll
    for (int mt = 0; mt < 4; ++mt) {
        curA[mt] = *(const float4*)(xr + rowoff[mt]);
        curB[mt] = *(const float4*)(xr + rowoff[mt] + 4);
    }

    __syncthreads();   // wbl visible

    #pragma unroll 1
    for (int kk = 0; kk < 8; ++kk) {
        if (kk < 7) {   // issue next-kk loads first; they fly across the MFMAs
            const int o = (kk + 1) << 5;
            #pragma unroll
            for (int mt = 0; mt < 4; ++mt) {
                nxtA[mt] = *(const float4*)(xr + rowoff[mt] + o);
                nxtB[mt] = *(const float4*)(xr + rowoff[mt] + o + 4);
            }
        }
        // B-frags for this k-step: (nt, split)
        short8 B[2][2];
        #pragma unroll
        for (int nt = 0; nt < 2; ++nt)
            #pragma unroll
            for (int sp = 0; sp < 2; ++sp) {
                const int fb = ((((kk << 1) + nt) << 1) + sp) * 256 + (l << 2);
                B[nt][sp] = __builtin_bit_cast(short8, *(const f4v*)&wbl[fb]);
            }
        #pragma unroll
        for (int mt = 0; mt < 4; ++mt) {
            const float4 pa = curA[mt], pb = curB[mt];
            psum[mt] += ((pa.x + pa.y) + (pa.z + pa.w)) + ((pb.x + pb.y) + (pb.z + pb.w));
            pssq[mt]  = fmaf(pa.x, pa.x, fmaf(pa.y, pa.y, fmaf(pa.z, pa.z, fmaf(pa.w, pa.w, pssq[mt]))));
            pssq[mt]  = fmaf(pb.x, pb.x, fmaf(pb.y, pb.y, fmaf(pb.z, pb.z, fmaf(pb.w, pb.w, pssq[mt]))));
            uint4 u1, u2;
            u1.x = pk_bf16(pa.x, pa.y); u1.y = pk_bf16(pa.z, pa.w);
            u1.z = pk_bf16(pb.x, pb.y); u1.w = pk_bf16(pb.z, pb.w);
            u2.x = pk_bf16(pa.x - trunc_bf16(pa.x), pa.y - trunc_bf16(pa.y));
            u2.y = pk_bf16(pa.z - trunc_bf16(pa.z), pa.w - trunc_bf16(pa.w));
            u2.z = pk_bf16(pb.x - trunc_bf16(pb.x), pb.y - trunc_bf16(pb.y));
            u2.w = pk_bf16(pb.z - trunc_bf16(pb.z), pb.w - trunc_bf16(pb.w));
            const short8 A1 = __builtin_bit_cast(short8, u1);
            const short8 A2 = __builtin_bit_cast(short8, u2);
            acc[mt][0] = __builtin_amdgcn_mfma_f32_16x16x32_bf16(A1, B[0][0], acc[mt][0], 0, 0, 0);
            acc[mt][1] = __builtin_amdgcn_mfma_f32_16x16x32_bf16(A1, B[1][0], acc[mt][1], 0, 0, 0);
            acc[mt][0] = __builtin_amdgcn_mfma_f32_16x16x32_bf16(A1, B[0][1], acc[mt][0], 0, 0, 0);
            acc[mt][1] = __builtin_amdgcn_mfma_f32_16x16x32_bf16(A1, B[1][1], acc[mt][1], 0, 0, 0);
            acc[mt][0] = __builtin_amdgcn_mfma_f32_16x16x32_bf16(A2, B[0][0], acc[mt][0], 0, 0, 0);
            acc[mt][1] = __builtin_amdgcn_mfma_f32_16x16x32_bf16(A2, B[1][0], acc[mt][1], 0, 0, 0);
        }
        if (kk < 7) {
            #pragma unroll
            for (int mt = 0; mt < 4; ++mt) { curA[mt] = nxtA[mt]; curB[mt] = nxtB[mt]; }
        }
    }

    // ---- stats: reduce over the 4 k-groups (lanes l^16, l^32), publish ----
    #pragma unroll
    for (int mt = 0; mt < 4; ++mt) {
        float s1 = psum[mt], s2 = pssq[mt];
        s1 += __shfl_xor(s1, 16); s1 += __shfl_xor(s1, 32);
        s2 += __shfl_xor(s2, 16); s2 += __shfl_xor(s2, 32);
        if (l < 16) {
            const int s = (w << 6) + (mt << 4) + lr;
            const float mu  = s1 * (1.f / CM);
            const float var = s2 * (1.f / CM) - mu * mu;
            st[s]       = mu;
            st[256 + s] = 1.f / sqrtf(var + EPS);
        }
    }
    __syncthreads();   // (B) stats visible; all B-frag reads done

    // ---------------- P2: LN-fold -> a[s][32] in wbl region, XOR-swizzled ----------------
    float* aB = (float*)wbl;
    {
        const int cl = lr;
        const float k1_0 = k12[cl],      k1_1 = k12[16 + cl];
        const float k2_0 = k12[CC + cl], k2_1 = k12[CC + 16 + cl];
        #pragma unroll
        for (int mt = 0; mt < 4; ++mt) {
            #pragma unroll
            for (int rg = 0; rg < 4; ++rg) {
                const int s = (w << 6) + (mt << 4) + (lk << 2) + rg;
                const float mu = st[s], rs = st[256 + s];
                const float a0 = fmaf(rs, acc[mt][0][rg] - mu * k1_0, k2_0);
                const float a1 = fmaf(rs, acc[mt][1][rg] - mu * k1_1, k2_1);
                const int sw = s & 7;
                aB[s * CC + (((cl >> 2) ^ sw) << 2) + (cl & 3)]       = a0;
                aB[s * CC + ((((cl >> 2) + 4) ^ sw) << 2) + (cl & 3)] = a1;
            }
        }
    }
    __syncthreads();   // (C) a complete

    // ---------------- P3: o = A^T A / NSEQ, split-K(4) x 4x4 tiles ----------------
    const int grp = w;                 // s-slice 64*grp .. +63
    const int xs_ = (tid >> 3) & 7;    // row f4-slot
    const int ys_ = tid & 7;           // col f4-slot
    float4 pr0 = {0,0,0,0}, pr1 = {0,0,0,0}, pr2 = {0,0,0,0}, pr3 = {0,0,0,0};
    #pragma unroll 4
    for (int si = 0; si < 64; ++si) {
        const int s  = (grp << 6) + si;
        const int sw = s & 7;
        const float4 ax = *(const float4*)&aB[s * CC + ((xs_ ^ sw) << 2)];
        const float4 ay = *(const float4*)&aB[s * CC + ((ys_ ^ sw) << 2)];
        pr0.x = fmaf(ax.x, ay.x, pr0.x); pr0.y = fmaf(ax.x, ay.y, pr0.y);
        pr0.z = fmaf(ax.x, ay.z, pr0.z); pr0.w = fmaf(ax.x, ay.w, pr0.w);
        pr1.x = fmaf(ax.y, ay.x, pr1.x); pr1.y = fmaf(ax.y, ay.y, pr1.y);
        pr1.z = fmaf(ax.y, ay.z, pr1.z); pr1.w = fmaf(ax.y, ay.w, pr1.w);
        pr2.x = fmaf(ax.z, ay.x, pr2.x); pr2.y = fmaf(ax.z, ay.y, pr2.y);
        pr2.z = fmaf(ax.z, ay.z, pr2.z); pr2.w = fmaf(ax.z, ay.w, pr2.w);
        pr3.x = fmaf(ax.w, ay.x, pr3.x); pr3.y = fmaf(ax.w, ay.y, pr3.y);
        pr3.z = fmaf(ax.w, ay.z, pr3.z); pr3.w = fmaf(ax.w, ay.w, pr3.w);
    }
    {
        float* pb = &scr[(grp << 10) + ((xs_ << 2) * CC) + (ys_ << 2)];
        *(float4*)&pb[0 * CC] = pr0;
        *(float4*)&pb[1 * CC] = pr1;
        *(float4*)&pb[2 * CC] = pr2;
        *(float4*)&pb[3 * CC] = pr3;
    }
    __syncthreads();   // (D) partials visible
    {
        const float inv_s = 1.f / NSEQ;
        float4 a4 = *(const float4*)&scr[(tid << 2)];
        const float4 b1 = *(const float4*)&scr[1024 + (tid << 2)];
        const float4 b2 = *(const float4*)&scr[2048 + (tid << 2)];
        const float4 b3 = *(const float4*)&scr[3072 + (tid << 2)];
        a4.x = (a4.x + b1.x + b2.x + b3.x) * inv_s;
        a4.y = (a4.y + b1.y + b2.y + b3.y) * inv_s;
        a4.z = (a4.z + b1.z + b2.z + b3.z) * inv_s;
        a4.w = (a4.w + b1.w + b2.w + b3.w) * inv_s;
        *(float4*)&scr[tid << 2] = a4;
    }
    __syncthreads();   // (E) o visible

    // ---------------- P4: pre[z] = o . w_out[z] + b_out[z] ----------------
    {
        const int z    = tid & 127;
        const int half = tid >> 7;
        const float* wrow = w_out + (size_t)z * (CC * CC) + half * 512;
        const float* op   = &scr[half * 512];
        float po = 0.f;
        #pragma unroll 8
        for (int k = 0; k < 512; k += 4) {
            const float4 o4 = *(const float4*)&op[k];
            const float4 w4 = *(const float4*)&wrow[k];
            po = fmaf(o4.x, w4.x, fmaf(o4.y, w4.y, fmaf(o4.z, w4.z, fmaf(o4.w, w4.w, po))));
        }
        scr[4096 + (half << 7) + z] = po;
    }
    __syncthreads();   // (F)
    if (tid < CZ)
        pre_out[(size_t)r * CZ + tid] = scr[4096 + tid] + scr[4096 + CZ + tid] + b_out[tid];
}

// ===================== Kernel B: broadcast pre over 1024 rows =====================
__launch_bounds__(256, 8)
__global__ void opm_bcast(const float* __restrict__ pre,
                          float* __restrict__ out)
{
    const int bid = blockIdx.x;
    const int r   = bid >> 3;                 // 0..1023
    const int jb  = bid & 7;                  // 128-row slab within the r-plane
    const int z4  = threadIdx.x & 31;         // which float4 of the 128-float row
    const int jo  = threadIdx.x >> 5;         // 0..7

    const f4v pv = *((const f4v*)(pre + (size_t)r * CZ) + z4);
    f4v* outp = (f4v*)out + ((size_t)r * NRES + (size_t)jb * 128) * (CZ / 4);
    for (int j0 = 0; j0 < 128; j0 += 8)
        __builtin_nontemporal_store(pv, &outp[(size_t)(j0 + jo) * (CZ / 4) + z4]);
}

extern "C" void kernel_launch(void* const* d_in, const int* in_sizes, int n_in,
                              void* d_out, int out_size, void* d_ws, size_t ws_size,
                              hipStream_t stream) {
    const float* msa   = (const float*)d_in[0];
    const float* nw    = (const float*)d_in[1];
    const float* nb    = (const float*)d_in[2];
    const float* w_ab  = (const float*)d_in[3];
    const float* b_ab  = (const float*)d_in[4];
    const float* w_out = (const float*)d_in[5];
    const float* b_out = (const float*)d_in[6];
    float* out = (float*)d_out;

    float* pre = (float*)d_ws;                           // [0, 131072) floats
    float* k12 = pre + (size_t)NRES * CZ;                // [131072, 131136)
    unsigned short* wb_su = (unsigned short*)(k12 + 64); // 16384 bf16 (32 KB), 16B-aligned

    opm_setup<<<1, 256, 0, stream>>>(nw, nb, w_ab, b_ab, k12, wb_su);
    opm_compute<<<NRES, 256, 0, stream>>>(msa, (const u32*)wb_su, k12, w_out, b_out, pre);
    opm_bcast<<<NRES * 8, 256, 0, stream>>>(pre, out);
}